// Round 3
// baseline (50.372 us; speedup 1.0000x reference)
//
#include <hip/hip_runtime.h>

// Problem constants: B,D,K,CI,CO,L,NB,P,S = 4,32,8,2,2,4096,15,7,8
constexpr int Bc  = 4;
constexpr int Dc  = 32;
constexpr int Kc  = 8;
constexpr int CIc = 2;
constexpr int COc = 2;
constexpr int Lc  = 4096;
constexpr int NBc = 15;
constexpr int Sc  = 8;

constexpr int TILE     = 1024;   // l positions per block
constexpr int NTHREADS = 256;    // each thread: 4 consecutive l, both co
constexpr int WELEMS   = COc * CIc * Sc * NBc;  // 480 weights per (d,k)

// seg(l): first 7 segments are 499 wide, last is 603 -> min(l/499, 7)
__device__ __forceinline__ int seg_of(int l) {
    int s = l / 499;
    return s > 7 ? 7 : s;
}

__global__ __launch_bounds__(NTHREADS, 4) void cde_bcr_kernel(
    const float* __restrict__ x,     // [B][D][K][CI][L]
    const float* __restrict__ w,     // [D][K][CO][CI][S][1][NB]
    const float* __restrict__ bias,  // [D][K][CO][S][1]
    float* __restrict__ out)         // [B][D][K][CO][L]
{
    // xs index = (l - lbase) + 8
    __shared__ __align__(16) float xs[CIc][TILE + 16];
    __shared__ __align__(16) float wl[COc * CIc * Sc][16]; // row r=(o*CI+i)*S+s, f padded 15->16
    __shared__ float bl[COc * Sc];

    const int tid   = threadIdx.x;
    const int lbase = blockIdx.x * TILE;
    const int bdk   = blockIdx.y;            // ((b*D + d)*K + k)
    const int dk    = bdk % (Dc * Kc);

    // ---- stage weights (480 floats over 256 threads) + bias (16) ----
    for (int t = tid; t < WELEMS; t += NTHREADS) {
        wl[t / NBc][t % NBc] = w[(size_t)dk * WELEMS + t];
    }
    if (tid < COc * Sc) {
        bl[tid] = bias[(size_t)dk * (COc * Sc) + tid];
    }

    // ---- stage x interior: 2 ci rows of TILE floats, aligned float4 ----
    const float* xb = x + (size_t)bdk * CIc * Lc;
#pragma unroll
    for (int i = 0; i < CIc; ++i) {
        float4 v = *(const float4*)(xb + (size_t)i * Lc + lbase + tid * 4);
        *(float4*)&xs[i][8 + tid * 4] = v;
    }
    // ---- halos: left idx [0,8), right idx [8+TILE, 8+TILE+8) ----
    if (tid < 2 * CIc * 8) {
        int which = tid / (CIc * 8);         // 0 = left, 1 = right
        int rem   = tid % (CIc * 8);
        int i = rem / 8, e = rem % 8;
        int idx = which ? (8 + TILE + e) : e;
        int l   = lbase + (which ? (TILE + e) : (e - 8));
        float v = (l >= 0 && l < Lc) ? xb[(size_t)i * Lc + l] : 0.0f;
        xs[i][idx] = v;
    }
    __syncthreads();

    const int l0  = tid * 4;
    const int gl0 = lbase + l0;
    const int s0  = seg_of(gl0);
    const int s3  = seg_of(gl0 + 3);

    float acc[COc][4];

    // ---- uniform fast path with s0 for all 4 outputs ----
#pragma unroll
    for (int o = 0; o < COc; ++o)
#pragma unroll
        for (int j = 0; j < 4; ++j)
            acc[o][j] = bl[o * Sc + s0];

#pragma unroll
    for (int i = 0; i < CIc; ++i) {
        // x window: xs idx [l0, l0+20) covers j+f+1 in [1,18]
        float xa[20];
#pragma unroll
        for (int m = 0; m < 20; ++m)
            xa[m] = xs[i][l0 + m];
        float w0[NBc], w1[NBc];
#pragma unroll
        for (int f = 0; f < NBc; ++f) {
            w0[f] = wl[(0 * CIc + i) * Sc + s0][f];
            w1[f] = wl[(1 * CIc + i) * Sc + s0][f];
        }
#pragma unroll
        for (int f = 0; f < NBc; ++f) {
#pragma unroll
            for (int j = 0; j < 4; ++j) {
                float xv = xa[j + f + 1];
                acc[0][j] = fmaf(w0[f], xv, acc[0][j]);
                acc[1][j] = fmaf(w1[f], xv, acc[1][j]);
            }
        }
    }

    // ---- fixup: thread straddles a segment boundary (7 threads per bdk row).
    // Segments are monotone and >=499 wide, so s3 == s0+1 and positions
    // j >= jstart all belong to segment s3. Exec-masked to ~1 lane per wave.
    if (s3 != s0) {
        const int jstart = 499 * s3 - gl0;   // in [1,3]
        const float b0 = bl[0 * Sc + s3];
        const float b1 = bl[1 * Sc + s3];
        for (int j = jstart; j < 4; ++j) {
            float a0 = b0, a1 = b1;
            for (int i = 0; i < CIc; ++i)
                for (int f = 0; f < NBc; ++f) {
                    float xv = xs[i][l0 + j + f + 1];
                    a0 = fmaf(wl[(0 * CIc + i) * Sc + s3][f], xv, a0);
                    a1 = fmaf(wl[(1 * CIc + i) * Sc + s3][f], xv, a1);
                }
            acc[0][j] = a0;
            acc[1][j] = a1;
        }
    }

    // ---- store: 2 coalesced float4 stores ----
    float* ob = out + (size_t)bdk * COc * Lc + lbase + l0;
    *(float4*)&ob[0]  = make_float4(acc[0][0], acc[0][1], acc[0][2], acc[0][3]);
    *(float4*)&ob[Lc] = make_float4(acc[1][0], acc[1][1], acc[1][2], acc[1][3]);
}

extern "C" void kernel_launch(void* const* d_in, const int* in_sizes, int n_in,
                              void* d_out, int out_size, void* d_ws, size_t ws_size,
                              hipStream_t stream) {
    const float* x    = (const float*)d_in[0];
    const float* w    = (const float*)d_in[1];
    const float* bias = (const float*)d_in[2];
    float* out        = (float*)d_out;

    dim3 grid(Lc / TILE, Bc * Dc * Kc);   // 4 x 1024 blocks
    cde_bcr_kernel<<<grid, NTHREADS, 0, stream>>>(x, w, bias, out);
}

// Round 4
// 30.243 us; speedup vs baseline: 1.6656x; 1.6656x over previous
//
#include <hip/hip_runtime.h>

// Problem constants: B,D,K,CI,CO,L,NB,P,S = 4,32,8,2,2,4096,15,7,8
constexpr int Bc  = 4;
constexpr int Dc  = 32;
constexpr int Kc  = 8;
constexpr int CIc = 2;
constexpr int COc = 2;
constexpr int Lc  = 4096;
constexpr int NBc = 15;
constexpr int Sc  = 8;

constexpr int NTHREADS = 256;
constexpr int JT       = 4;                  // outputs per thread per co
constexpr int TILE     = NTHREADS * JT;      // 1024 l per block
constexpr int WELEMS   = COc * CIc * Sc * NBc;  // 480

// seg(l) = min(l/499, 7)
__device__ __forceinline__ int seg_of(int l) {
    int s = l / 499;
    return s > 7 ? 7 : s;
}

__global__ __launch_bounds__(NTHREADS) void cde_bcr_kernel(
    const float* __restrict__ x,     // [B][D][K][CI][L]
    const float* __restrict__ w,     // [D][K][CO][CI][S][1][NB]
    const float* __restrict__ bias,  // [D][K][CO][S][1]
    float* __restrict__ out)         // [B][D][K][CO][L]
{
    // Only weights + bias in LDS (broadcast reads). x comes straight from global/L1.
    __shared__ __align__(16) float wl[COc * CIc * Sc][16]; // row=(o*CI+i)*S+s, f padded 15->16
    __shared__ float bl[COc * Sc];

    const int tid   = threadIdx.x;
    const int lbase = blockIdx.x * TILE;
    const int bdk   = blockIdx.y;            // ((b*D + d)*K + k)
    const int dk    = bdk % (Dc * Kc);

    for (int t = tid; t < WELEMS; t += NTHREADS)
        wl[t / NBc][t % NBc] = w[(size_t)dk * WELEMS + t];
    if (tid < COc * Sc)
        bl[tid] = bias[(size_t)dk * (COc * Sc) + tid];
    __syncthreads();

    const int l0  = tid * JT;
    const int gl0 = lbase + l0;
    const int s0  = seg_of(gl0);
    const int s3  = seg_of(gl0 + JT - 1);

    const float* xb = x + (size_t)bdk * CIc * Lc;

    float acc[COc][JT];
#pragma unroll
    for (int o = 0; o < COc; ++o)
#pragma unroll
        for (int j = 0; j < JT; ++j)
            acc[o][j] = bl[o * Sc + s0];

#pragma unroll
    for (int i = 0; i < CIc; ++i) {
        // window xa[m] = x[gl0 - 8 + m], m in [0,20); out(j,f) uses xa[j+f+1]
        float xa[20];
        const float* xi = xb + (size_t)i * Lc + gl0;
        if (gl0 >= 8 && gl0 + 12 <= Lc) {
            // aligned (gl0 % 4 == 0): 5 x global_load_dwordx4, heavy L1 reuse
#pragma unroll
            for (int m = 0; m < 5; ++m)
                *(float4*)&xa[4 * m] = *(const float4*)(xi - 8 + 4 * m);
        } else {
            // row edges: 2 threads per end per bdk row, exec-masked
#pragma unroll
            for (int m = 0; m < 20; ++m) {
                int l = gl0 - 8 + m;
                xa[m] = (l >= 0 && l < Lc) ? xi[m - 8] : 0.0f;
            }
        }

        // weights: broadcast LDS reads (all lanes same s0 except near boundary -> 2-way, free)
        float w0[16], w1[16];
#pragma unroll
        for (int m = 0; m < 4; ++m) {
            *(float4*)&w0[4 * m] = *(const float4*)&wl[(0 * CIc + i) * Sc + s0][4 * m];
            *(float4*)&w1[4 * m] = *(const float4*)&wl[(1 * CIc + i) * Sc + s0][4 * m];
        }

#pragma unroll
        for (int f = 0; f < NBc; ++f) {
#pragma unroll
            for (int j = 0; j < JT; ++j) {
                float xv = xa[j + f + 1];
                acc[0][j] = fmaf(w0[f], xv, acc[0][j]);
                acc[1][j] = fmaf(w1[f], xv, acc[1][j]);
            }
        }
    }

    // fixup: thread straddles a segment boundary (7 threads per bdk row), masked
    if (s3 != s0) {
        const int jstart = 499 * s3 - gl0;   // in [1, JT-1]
        for (int j = jstart; j < JT; ++j) {
            float a0 = bl[0 * Sc + s3];
            float a1 = bl[1 * Sc + s3];
            for (int i = 0; i < CIc; ++i) {
                const float* xi = xb + (size_t)i * Lc;
                for (int f = 0; f < NBc; ++f) {
                    int l = gl0 + j + f - 7;
                    float xv = (l >= 0 && l < Lc) ? xi[l] : 0.0f;
                    a0 = fmaf(wl[(0 * CIc + i) * Sc + s3][f], xv, a0);
                    a1 = fmaf(wl[(1 * CIc + i) * Sc + s3][f], xv, a1);
                }
            }
            acc[0][j] = a0;
            acc[1][j] = a1;
        }
    }

    // store: 2 coalesced float4 stores per thread
    float* ob = out + (size_t)bdk * COc * Lc + lbase + l0;
    *(float4*)&ob[0]  = make_float4(acc[0][0], acc[0][1], acc[0][2], acc[0][3]);
    *(float4*)&ob[Lc] = make_float4(acc[1][0], acc[1][1], acc[1][2], acc[1][3]);
}

extern "C" void kernel_launch(void* const* d_in, const int* in_sizes, int n_in,
                              void* d_out, int out_size, void* d_ws, size_t ws_size,
                              hipStream_t stream) {
    const float* x    = (const float*)d_in[0];
    const float* w    = (const float*)d_in[1];
    const float* bias = (const float*)d_in[2];
    float* out        = (float*)d_out;

    dim3 grid(Lc / TILE, Bc * Dc * Kc);   // 4 x 1024 blocks
    cde_bcr_kernel<<<grid, NTHREADS, 0, stream>>>(x, w, bias, out);
}

// Round 6
// 22.213 us; speedup vs baseline: 2.2677x; 1.3615x over previous
//
#include <hip/hip_runtime.h>

// Problem constants: B,D,K,CI,CO,L,NB,P,S = 4,32,8,2,2,4096,15,7,8
constexpr int Bc  = 4;
constexpr int Dc  = 32;
constexpr int Kc  = 8;
constexpr int CIc = 2;
constexpr int COc = 2;
constexpr int Lc  = 4096;
constexpr int NBc = 15;
constexpr int Sc  = 8;

constexpr int NTHREADS = 256;
constexpr int JT       = 8;                  // outputs per thread per co
constexpr int TILE     = NTHREADS * JT;      // 2048 l per block
constexpr int WELEMS   = COc * CIc * Sc * NBc;  // 480
constexpr int WIN      = JT + 16;            // 24-float x window per ci

typedef float f32x4 __attribute__((ext_vector_type(4)));  // native vec for nontemporal builtin

// seg(l) = min(l/499, 7)
__device__ __forceinline__ int seg_of(int l) {
    int s = l / 499;
    return s > 7 ? 7 : s;
}

__global__ __launch_bounds__(NTHREADS) void cde_bcr_kernel(
    const float* __restrict__ x,     // [B][D][K][CI][L]
    const float* __restrict__ w,     // [D][K][CO][CI][S][1][NB]
    const float* __restrict__ bias,  // [D][K][CO][S][1]
    float* __restrict__ out)         // [B][D][K][CO][L]
{
    // Only weights + bias in LDS (broadcast reads). x comes straight from global/L1.
    __shared__ __align__(16) float wl[COc * CIc * Sc][16]; // row=(o*CI+i)*S+s
    __shared__ float bl[COc * Sc];

    const int tid   = threadIdx.x;
    const int lbase = blockIdx.x * TILE;
    const int bdk   = blockIdx.y;            // ((b*D + d)*K + k)
    const int dk    = bdk % (Dc * Kc);

    for (int t = tid; t < WELEMS; t += NTHREADS)
        wl[t / NBc][t % NBc] = w[(size_t)dk * WELEMS + t];
    if (tid < COc * Sc)
        bl[tid] = bias[(size_t)dk * (COc * Sc) + tid];
    __syncthreads();

    const int l0  = tid * JT;
    const int gl0 = lbase + l0;
    const int s0  = seg_of(gl0);
    const int s7  = seg_of(gl0 + JT - 1);

    const float* xb = x + (size_t)bdk * CIc * Lc;

    // ---- load both ci windows up front: xa_i[m] = x[i][gl0 - 8 + m], m in [0,24)
    // out(j,f) uses xa[j+f+1] (j<8, f<15 -> m in [1,23))
    float xa0[WIN], xa1[WIN];
    const float* xi0 = xb + gl0;
    const float* xi1 = xb + Lc + gl0;
    if (gl0 >= 8 && gl0 + 16 <= Lc) {
        // aligned (gl0 % 4 == 0): 12 independent global_load_dwordx4
#pragma unroll
        for (int m = 0; m < WIN / 4; ++m)
            *(f32x4*)&xa0[4 * m] = *(const f32x4*)(xi0 - 8 + 4 * m);
#pragma unroll
        for (int m = 0; m < WIN / 4; ++m)
            *(f32x4*)&xa1[4 * m] = *(const f32x4*)(xi1 - 8 + 4 * m);
    } else {
        // row edges (2 threads per bdk row), exec-masked, bounds-clamped
#pragma unroll
        for (int m = 0; m < WIN; ++m) {
            int l = gl0 - 8 + m;
            bool ok = (l >= 0 && l < Lc);
            xa0[m] = ok ? xi0[m - 8] : 0.0f;
            xa1[m] = ok ? xi1[m - 8] : 0.0f;
        }
    }

    float acc[COc][JT];
#pragma unroll
    for (int o = 0; o < COc; ++o)
#pragma unroll
        for (int j = 0; j < JT; ++j)
            acc[o][j] = bl[o * Sc + s0];

    // ---- main FMA block, uniform segment s0 ----
#pragma unroll
    for (int i = 0; i < CIc; ++i) {
        float w0[16], w1[16];
#pragma unroll
        for (int m = 0; m < 4; ++m) {
            *(f32x4*)&w0[4 * m] = *(const f32x4*)&wl[(0 * CIc + i) * Sc + s0][4 * m];
            *(f32x4*)&w1[4 * m] = *(const f32x4*)&wl[(1 * CIc + i) * Sc + s0][4 * m];
        }
#pragma unroll
        for (int f = 0; f < NBc; ++f) {
#pragma unroll
            for (int j = 0; j < JT; ++j) {
                float xv = (i == 0) ? xa0[j + f + 1] : xa1[j + f + 1];
                acc[0][j] = fmaf(w0[f], xv, acc[0][j]);
                acc[1][j] = fmaf(w1[f], xv, acc[1][j]);
            }
        }
    }

    // ---- fixup: thread straddles a segment boundary (<=7 threads per bdk row).
    // ALL indices compile-time (rule #20: no runtime-indexed register arrays).
    if (s7 != s0) {
        const int jstart = 499 * s7 - gl0;   // in [1, JT-1]
        const float b0 = bl[0 * Sc + s7];
        const float b1 = bl[1 * Sc + s7];
#pragma unroll
        for (int j = 0; j < JT; ++j) {
            if (j >= jstart) {
                float a0 = b0, a1 = b1;
#pragma unroll
                for (int i = 0; i < CIc; ++i) {
#pragma unroll
                    for (int f = 0; f < NBc; ++f) {
                        float xv = (i == 0) ? xa0[j + f + 1] : xa1[j + f + 1];
                        a0 = fmaf(wl[(0 * CIc + i) * Sc + s7][f], xv, a0);
                        a1 = fmaf(wl[(1 * CIc + i) * Sc + s7][f], xv, a1);
                    }
                }
                acc[0][j] = a0;
                acc[1][j] = a1;
            }
        }
    }

    // ---- store: 4 nontemporal float4 stores (output is write-only, spare the L2) ----
    float* ob = out + (size_t)bdk * COc * Lc + gl0;
#pragma unroll
    for (int o = 0; o < COc; ++o) {
        f32x4 v0 = { acc[o][0], acc[o][1], acc[o][2], acc[o][3] };
        f32x4 v1 = { acc[o][4], acc[o][5], acc[o][6], acc[o][7] };
        __builtin_nontemporal_store(v0, (f32x4*)(ob + (size_t)o * Lc));
        __builtin_nontemporal_store(v1, (f32x4*)(ob + (size_t)o * Lc + 4));
    }
}

extern "C" void kernel_launch(void* const* d_in, const int* in_sizes, int n_in,
                              void* d_out, int out_size, void* d_ws, size_t ws_size,
                              hipStream_t stream) {
    const float* x    = (const float*)d_in[0];
    const float* w    = (const float*)d_in[1];
    const float* bias = (const float*)d_in[2];
    float* out        = (float*)d_out;

    dim3 grid(Lc / TILE, Bc * Dc * Kc);   // 2 x 1024 blocks
    cde_bcr_kernel<<<grid, NTHREADS, 0, stream>>>(x, w, bias, out);
}